// Round 7
// baseline (236.128 us; speedup 1.0000x reference)
//
#include <hip/hip_runtime.h>

// CtaPostAttnMixer: y = (I + 0.1*Lap)^4 x along l, boundaries l=0, L-1 fixed.
// One 9-tap convolution (interior) + analytic boundary rows.
// x: (B=4, L=8192, D=1024) f32, D contiguous.
//
// R3/R5/R6: register-held windows get serialized by the allocator. Dead end.
// R7/R9: LDS-staged tiles (amp 1.25) run ~72-78us at BOTH 50% and 87%
//   occupancy -> occupancy is not the knob. Per-CU demand rate ~15 GB/s/CU
//   vs 26 GB/s/CU proven by the register kernel / fill / m13 copy.
//   Diagnosis: stage -> __syncthreads (s_waitcnt vmcnt(0) drain) -> compute
//   serializes each block; block generations convoy -> CU-wide dead windows.
// R8: pipelining attempt failed BECAUSE __syncthreads drains the prefetch
//   (true dep at depth 2) + 18% occupancy.
// R10 (this round): T3/T4 minimum recipe in plain HIP. Persistent 1024
//   blocks (exactly 4/CU, all resident), each marches 8 consecutive
//   32-row tiles, double-buffered 20 KB tiles (40 KB LDS). Counted
//   s_waitcnt vmcnt(N) + RAW s_barrier: next-tile DMAs stay in flight
//   across the barrier. Per-wave vmem ledger per iter = 5 DMAs + 4 stores:
//   steady wait = vmcnt(9) (4 ST + 5 new DMAs allowed outstanding),
//   prologue vmcnt(5), epilogue vmcnt(4). Waits BEFORE the barrier (each
//   wave certifies its own DMAs; barrier makes it collective).
//   Predict mixer ~45-55us, total ~200-212. Null (>=72) indicts the
//   global_load_lds path itself -> next: buffer_load->ds_write relay.

namespace {

constexpr int Lr   = 8192;           // sequence length
constexpr int Dq   = 1024 / 4;       // float4 columns = 256
constexpr int Bn   = 4;              // batch
constexpr int R    = 32;             // output rows per tile
constexpr int WR   = R + 8;          // staged rows = 40
constexpr int CW   = 32;             // float4 columns per block (512 B rows)
constexpr int RT   = Lr / R;         // 256 row tiles per strip
constexpr int CT   = Dq / CW;        // 8 col tiles
constexpr int MT   = 8;              // tiles marched per block
constexpr int NXCD = 8;
constexpr int NWG  = RT * CT * Bn / MT;  // 1024 blocks = 4/CU, all resident

// standard 9-tap weights of (I + a*Lap)^4, a = 0.1 (exact: p=[.1,.8,.1]^*4)
constexpr float WK0 = 0.4870f;
constexpr float WK1 = 0.2144f;
constexpr float WK2 = 0.0388f;
constexpr float WK3 = 0.0032f;
constexpr float WK4 = 0.0001f;

#define WAITCNT_VM(n) asm volatile("s_waitcnt vmcnt(" #n ")" ::: "memory")
#define MEMFENCE()    asm volatile("" ::: "memory")

__device__ __forceinline__ float4 f4_add(float4 a, float4 b) {
    return make_float4(a.x + b.x, a.y + b.y, a.z + b.z, a.w + b.w);
}
__device__ __forceinline__ float4 f4_mul(float s, float4 a) {
    return make_float4(s * a.x, s * a.y, s * a.z, s * a.w);
}
__device__ __forceinline__ float4 f4_fma(float s, float4 a, float4 c) {
    return make_float4(fmaf(s, a.x, c.x), fmaf(s, a.y, c.y),
                       fmaf(s, a.z, c.z), fmaf(s, a.w, c.w));
}

__global__ __launch_bounds__(256, 4)   // 4 blocks/CU (LDS 40KB each), VGPR<=128
void mixer4_kernel(const float4* __restrict__ x, float4* __restrict__ y) {
    __shared__ float4 buf[2][WR][CW];  // 2 x 20 KB double buffer

    // XCD-aware bijective swizzle (NWG=1024, %8==0): XCD k owns 128
    // contiguous work ids -> a strip's marching blocks share one XCD's L2.
    const int lin   = blockIdx.x;                      // 0..1023
    const int g     = (lin & (NXCD - 1)) * (NWG / NXCD) + (lin >> 3);
    const int strip = g >> 5;            // 0..31  (32 marching blocks/strip)
    const int mrch  = g & 31;
    const int ct    = strip & (CT - 1);
    const int b     = strip >> 3;
    const int rt0   = mrch * MT;         // first row-tile of this march

    const size_t origin = (size_t)b * Lr * Dq + (size_t)ct * CW;
    const float4* __restrict__ xt = x + origin;
    float4* __restrict__       yt = y + origin;

    const int lane = threadIdx.x & 63;
    const int wid  = threadIdx.x >> 6;                 // wave 0..3

    // ---- stage tile rt into buf[sel]: 5 row-pair DMAs per wave (1 KB ea) -
    // LDS dest wave-uniform (&buf[sel][2p][0]); lanes 0-31 -> row 2p,
    // lanes 32-63 -> row 2p+1 (per-lane global source rows are legal).
    auto stage = [&](int rt, int sel) {
        const int r0s = rt * R;
#pragma unroll
        for (int ii = 0; ii < 5; ++ii) {
            const int p = wid + ii * 4;                // 0..19, once each
            int grow = r0s - 4 + 2 * p + (lane >> 5);
            grow = grow < 0 ? 0 : grow;
            grow = grow > Lr - 1 ? Lr - 1 : grow;
            const float4* src = xt + (size_t)grow * Dq + (lane & 31);
            __builtin_amdgcn_global_load_lds(
                (const __attribute__((address_space(1))) void*)src,
                (__attribute__((address_space(3))) void*)&buf[sel][2 * p][0],
                16, 0, 0);
        }
    };

    // ---- compute tile rt from buf[sel]: thread = (col c, rowgroup gr) ----
    const int c  = threadIdx.x & 31;
    const int gr = threadIdx.x >> 5;                   // 0..7, 4 rows each
    auto compute = [&](int rt, int sel) {
        const int r0 = rt * R;
        float4 win[12];                                // LDS rows 4gr..4gr+11
#pragma unroll
        for (int i = 0; i < 12; ++i) win[i] = buf[sel][4 * gr + i][c];
        // win[i] = x[r0 + 4gr - 4 + i (clamped)]

        auto interior = [&](int j) {   // output local row 4gr+j
            float4 acc = f4_mul(WK0, win[j + 4]);
            acc = f4_fma(WK1, f4_add(win[j + 3], win[j + 5]), acc);
            acc = f4_fma(WK2, f4_add(win[j + 2], win[j + 6]), acc);
            acc = f4_fma(WK3, f4_add(win[j + 1], win[j + 7]), acc);
            acc = f4_fma(WK4, f4_add(win[j + 0], win[j + 8]), acc);
            yt[(size_t)(r0 + 4 * gr + j) * Dq + c] = acc;
        };

        const bool low  = (rt == 0)      && (gr == 0); // global rows 0..3
        const bool high = (rt == RT - 1) && (gr == 7); // rows L-4..L-1

        if (low) {
            // win[4+m] = x[m] (rows -4..-1 staged as clamped dups of x[0])
            yt[0 * (size_t)Dq + c] = win[4];           // l=0: copy
            {   // l=1
                float4 o = f4_mul(0.2986f, win[4]);
                o = f4_fma(0.4482f, win[5], o);
                o = f4_fma(0.2112f, win[6], o);
                o = f4_fma(0.0387f, win[7], o);
                o = f4_fma(0.0032f, win[8], o);
                o = f4_fma(0.0001f, win[9], o);
                yt[1 * (size_t)Dq + c] = o;
            }
            {   // l=2
                float4 o = f4_mul(0.0454f, win[4]);
                o = f4_fma(0.2112f, win[5], o);
                o = f4_fma(0.4869f, win[6], o);
                o = f4_fma(0.2144f, win[7], o);
                o = f4_fma(0.0388f, win[8], o);
                o = f4_fma(0.0032f, win[9], o);
                o = f4_fma(0.0001f, win[10], o);
                yt[2 * (size_t)Dq + c] = o;
            }
            {   // l=3
                float4 o = f4_mul(0.0034f, win[4]);
                o = f4_fma(0.0387f, win[5], o);
                o = f4_fma(0.2144f, win[6], o);
                o = f4_fma(0.4870f, win[7], o);
                o = f4_fma(0.2144f, win[8], o);
                o = f4_fma(0.0388f, win[9], o);
                o = f4_fma(0.0032f, win[10], o);
                o = f4_fma(0.0001f, win[11], o);
                yt[3 * (size_t)Dq + c] = o;
            }
        } else if (high) {
            // gr==7, last tile: win[i] = x[L-8+i], i=0..7 (8..11 clamped)
            yt[(size_t)(Lr - 1) * Dq + c] = win[7];    // l=L-1: copy
            {   // l=L-2 (mirrored row1)
                float4 o = f4_mul(0.2986f, win[7]);
                o = f4_fma(0.4482f, win[6], o);
                o = f4_fma(0.2112f, win[5], o);
                o = f4_fma(0.0387f, win[4], o);
                o = f4_fma(0.0032f, win[3], o);
                o = f4_fma(0.0001f, win[2], o);
                yt[(size_t)(Lr - 2) * Dq + c] = o;
            }
            {   // l=L-3 (mirrored row2)
                float4 o = f4_mul(0.0454f, win[7]);
                o = f4_fma(0.2112f, win[6], o);
                o = f4_fma(0.4869f, win[5], o);
                o = f4_fma(0.2144f, win[4], o);
                o = f4_fma(0.0388f, win[3], o);
                o = f4_fma(0.0032f, win[2], o);
                o = f4_fma(0.0001f, win[1], o);
                yt[(size_t)(Lr - 3) * Dq + c] = o;
            }
            {   // l=L-4 (mirrored row3)
                float4 o = f4_mul(0.0034f, win[7]);
                o = f4_fma(0.0387f, win[6], o);
                o = f4_fma(0.2144f, win[5], o);
                o = f4_fma(0.4870f, win[4], o);
                o = f4_fma(0.2144f, win[3], o);
                o = f4_fma(0.0388f, win[2], o);
                o = f4_fma(0.0032f, win[1], o);
                o = f4_fma(0.0001f, win[0], o);
                yt[(size_t)(Lr - 4) * Dq + c] = o;
            }
        } else {
#pragma unroll
            for (int j = 0; j < 4; ++j) interior(j);
        }
    };

    // ---- counted-vmcnt double-buffered march -----------------------------
    // Per-wave vmem issue stream per iter: 5 DMAs (next tile) + 4 stores.
    // Prologue: 10 DMAs out -> vmcnt(5) proves tile0 landed.
    stage(rt0 + 0, 0);
    stage(rt0 + 1, 1);
    WAITCNT_VM(5);
    __builtin_amdgcn_s_barrier();
    MEMFENCE();
    compute(rt0 + 0, 0);
    MEMFENCE();
    __builtin_amdgcn_s_barrier();
    MEMFENCE();

    for (int t = 1; t < MT; ++t) {
        const int cur = t & 1;
        if (t + 1 < MT) {
            stage(rt0 + t + 1, cur ^ 1);   // 5 DMAs, stay in flight past barrier
            // stream (old->new): DMA(t) x5, ST(t-1) x4, DMA(t+1) x5
            // -> vmcnt(9) proves DMA(t) landed, keeps ST+new DMAs in flight.
            WAITCNT_VM(9);
        } else {
            // last tile: stream = DMA(t) x5, ST(t-1) x4 -> vmcnt(4).
            WAITCNT_VM(4);
        }
        __builtin_amdgcn_s_barrier();      // all waves certified their DMAs
        MEMFENCE();
        compute(rt0 + t, cur);             // ds_reads consumed before stores
        MEMFENCE();
        __builtin_amdgcn_s_barrier();      // readers done before next overwrite
        MEMFENCE();
    }
}

}  // namespace

extern "C" void kernel_launch(void* const* d_in, const int* in_sizes, int n_in,
                              void* d_out, int out_size, void* d_ws, size_t ws_size,
                              hipStream_t stream) {
    const float4* x = (const float4*)d_in[0];
    float4*       y = (float4*)d_out;

    dim3 grid(NWG);        // 1024 persistent blocks = 4/CU, all co-resident
    dim3 block(256);
    hipLaunchKernelGGL(mixer4_kernel, grid, block, 0, stream, x, y);
}